// Round 2
// baseline (5953.048 us; speedup 1.0000x reference)
//
#include <hip/hip_runtime.h>
#include <math.h>

#define HH 7
#define WW 18
#define PP 126        // HH*WW
#define CC 16
#define NN 4096
#define EE 16384
#define BB 64

__device__ __forceinline__ float sp_f(float x) {
    // softplus, JAX-stable form: max(x,0)+log1p(exp(-|x|))
    return fmaxf(x, 0.f) + log1pf(expf(-fabsf(x)));
}

// ---------------- weight transposes: [co][ci][tap] -> [tap][ci][co] ---------
// lin weights: nco=32
__global__ void k_wT(const float* __restrict__ w, float* __restrict__ wT) {
    int i = blockIdx.x * 256 + threadIdx.x;
    if (i < 32 * 144) {
        int co = i / 144, r = i - co * 144, ci = r / 9, tap = r - ci * 9;
        wT[(tap * 16 + ci) * 32 + co] = w[i];
    }
}
// node+edge weights packed: co<16 -> node, co>=16 -> edge
__global__ void k_wT2(const float* __restrict__ wN, const float* __restrict__ wE,
                      float* __restrict__ wT) {
    int i = blockIdx.x * 256 + threadIdx.x;
    if (i < 16 * 144) {
        int co = i / 144, r = i - co * 144, ci = r / 9, tap = r - ci * 9;
        wT[(tap * 16 + ci) * 32 + co] = wN[i];
        wT[(tap * 16 + ci) * 32 + co + 16] = wE[i];
    }
}

// ---------------- embedding: atom = softplus(conv1->16(nodes) + b) ----------
__global__ __launch_bounds__(256) void k_embed(const float* __restrict__ nodes,
                                               const float* __restrict__ w,
                                               const float* __restrict__ b,
                                               float* __restrict__ atom) {
    __shared__ float tile[PP];
    __shared__ float ws[CC * 9];
    __shared__ float bs[CC];
    int n = blockIdx.x, tid = threadIdx.x;
    for (int i = tid; i < PP; i += 256) tile[i] = nodes[n * PP + i];
    for (int i = tid; i < CC * 9; i += 256) ws[i] = w[i];
    if (tid < CC) bs[tid] = b[tid];
    __syncthreads();
    for (int i = tid; i < CC * PP; i += 256) {
        int c = i / PP, p = i - c * PP, y = p / WW, x = p - (p / WW) * WW;
        float acc = bs[c];
#pragma unroll
        for (int dy = 0; dy < 3; dy++) {
            int yy = y + dy - 1; if ((unsigned)yy >= (unsigned)HH) continue;
#pragma unroll
            for (int dx = 0; dx < 3; dx++) {
                int xx = x + dx - 1; if ((unsigned)xx >= (unsigned)WW) continue;
                acc += tile[yy * WW + xx] * ws[c * 9 + dy * 3 + dx];
            }
        }
        atom[(size_t)n * CC * PP + i] = sp_f(acc);
    }
}

// ------------- per-node dual conv 16->16, register-blocked ------------------
// wT layout [tap][ci][32]: co<16 node-weights, co>=16 edge-weights
__global__ __launch_bounds__(128) void k_node_conv2(const float* __restrict__ atom,
                                                    const float* __restrict__ wT,
                                                    float* __restrict__ An,
                                                    float* __restrict__ Ae) {
    __shared__ float z[CC][PP];
    __shared__ float ws[9][16][32];
    int n = blockIdx.x, tid = threadIdx.x;
    for (int i = tid; i < CC * PP; i += 128) ((float*)z)[i] = atom[(size_t)n * CC * PP + i];
    for (int i = tid; i < 9 * 16 * 32; i += 128) ((float*)ws)[i] = wT[i];
    __syncthreads();
    if (tid < 112) {
        int co = tid & 15, y = tid >> 4;
        float hN[18], hE[18];
#pragma unroll
        for (int x = 0; x < 18; x++) { hN[x] = 0.f; hE[x] = 0.f; }
        for (int ci = 0; ci < 16; ci++) {
#pragma unroll
            for (int dy = 0; dy < 3; dy++) {
                int yy = y + dy - 1;
                if ((unsigned)yy < (unsigned)HH) {
                    const float* zr = &z[ci][yy * 18];
                    float r[18];
#pragma unroll
                    for (int x = 0; x < 18; x++) r[x] = zr[x];
                    float wn0 = ws[dy * 3 + 0][ci][co];
                    float wn1 = ws[dy * 3 + 1][ci][co];
                    float wn2 = ws[dy * 3 + 2][ci][co];
                    float we0 = ws[dy * 3 + 0][ci][co + 16];
                    float we1 = ws[dy * 3 + 1][ci][co + 16];
                    float we2 = ws[dy * 3 + 2][ci][co + 16];
#pragma unroll
                    for (int x = 0; x < 18; x++) {
                        float an = r[x] * wn1, ae = r[x] * we1;
                        if (x > 0)  { an += r[x - 1] * wn0; ae += r[x - 1] * we0; }
                        if (x < 17) { an += r[x + 1] * wn2; ae += r[x + 1] * we2; }
                        hN[x] += an; hE[x] += ae;
                    }
                }
            }
        }
        float* pn = &An[(size_t)n * CC * PP + co * PP + y * 18];
        float* pe = &Ae[(size_t)n * CC * PP + co * PP + y * 18];
#pragma unroll
        for (int x = 0; x < 18; x++) { pn[x] = hN[x]; pe[x] = hE[x]; }
    }
}

// ---------------- per-edge: z=elu(An[s]*Ae[t]); h=conv16->32(z)+lb;
//                  msg=sigmoid(h[:16])*softplus(h[16:]); out[s] += msg -------
// lwT layout [tap][ci][32]: co<16 filter, co>=16 core
__global__ __launch_bounds__(128) void k_edge(const float* __restrict__ An,
                                              const float* __restrict__ Ae,
                                              const int* __restrict__ es,
                                              const int* __restrict__ et,
                                              const float* __restrict__ lwT,
                                              const float* __restrict__ lb,
                                              float* __restrict__ outb) {
    __shared__ float z[CC][PP];
    __shared__ float ws[9][16][32];
    int e = blockIdx.x, tid = threadIdx.x;
    int s = es[e], t = et[e];
    const float* an = &An[(size_t)s * CC * PP];
    const float* ae = &Ae[(size_t)t * CC * PP];
    for (int i = tid; i < CC * PP; i += 128) {
        float v = an[i] * ae[i];
        ((float*)z)[i] = v > 0.f ? v : expm1f(v);   // elu
    }
    for (int i = tid; i < 9 * 16 * 32; i += 128) ((float*)ws)[i] = lwT[i];
    __syncthreads();
    if (tid < 112) {
        int co = tid & 15, y = tid >> 4;
        float hf[18], hc[18];
#pragma unroll
        for (int x = 0; x < 18; x++) { hf[x] = 0.f; hc[x] = 0.f; }
        for (int ci = 0; ci < 16; ci++) {
#pragma unroll
            for (int dy = 0; dy < 3; dy++) {
                int yy = y + dy - 1;
                if ((unsigned)yy < (unsigned)HH) {
                    const float* zr = &z[ci][yy * 18];
                    float r[18];
#pragma unroll
                    for (int x = 0; x < 18; x++) r[x] = zr[x];
                    float wf0 = ws[dy * 3 + 0][ci][co];
                    float wf1 = ws[dy * 3 + 1][ci][co];
                    float wf2 = ws[dy * 3 + 2][ci][co];
                    float wc0 = ws[dy * 3 + 0][ci][co + 16];
                    float wc1 = ws[dy * 3 + 1][ci][co + 16];
                    float wc2 = ws[dy * 3 + 2][ci][co + 16];
#pragma unroll
                    for (int x = 0; x < 18; x++) {
                        float af = r[x] * wf1, ac = r[x] * wc1;
                        if (x > 0)  { af += r[x - 1] * wf0; ac += r[x - 1] * wc0; }
                        if (x < 17) { af += r[x + 1] * wf2; ac += r[x + 1] * wc2; }
                        hf[x] += af; hc[x] += ac;
                    }
                }
            }
        }
        float bf = lb[co], bc = lb[co + 16];
        float* outn = &outb[(size_t)s * CC * PP + co * PP + y * 18];
#pragma unroll
        for (int x = 0; x < 18; x++) {
            float hfv = hf[x] + bf, hcv = hc[x] + bc;
            float sig = 1.f / (1.f + expf(-hfv));
            float msg = sig * sp_f(hcv);
            unsafeAtomicAdd(&outn[x], msg);
        }
    }
}

// ---------------- BN statistics (double accumulation) -----------------------
template <int C, int S>
__global__ void k_bn_stats(const float* __restrict__ X, double* __restrict__ acc, int M) {
    int c = blockIdx.y, tid = threadIdx.x;
    double s1 = 0.0, s2 = 0.0;
    for (int m = blockIdx.x; m < M; m += gridDim.x) {
        const float* xr = &X[((size_t)m * C + c) * S];
        for (int s = tid; s < S; s += blockDim.x) {
            float v = xr[s];
            s1 += v; s2 += (double)v * v;
        }
    }
    __shared__ double sh1[256], sh2[256];
    sh1[tid] = s1; sh2[tid] = s2;
    __syncthreads();
    for (int off = blockDim.x >> 1; off > 0; off >>= 1) {
        if (tid < off) { sh1[tid] += sh1[tid + off]; sh2[tid] += sh2[tid + off]; }
        __syncthreads();
    }
    if (tid == 0) {
        unsafeAtomicAdd(&acc[2 * c], sh1[0]);
        unsafeAtomicAdd(&acc[2 * c + 1], sh2[0]);
    }
}

__global__ void k_bn_fin(const double* __restrict__ acc, const float* __restrict__ g,
                         const float* __restrict__ b, double invn,
                         float* __restrict__ scl, float* __restrict__ shf) {
    int c = threadIdx.x;
    if (c < 16) {
        double m = acc[2 * c] * invn;
        double v = acc[2 * c + 1] * invn - m * m;
        double s = (double)g[c] / sqrt(v + 1e-5);
        scl[c] = (float)s;
        shf[c] = (float)((double)b[c] - s * m);
    }
}

// atom += scl[c]*outb + shf[c]     (residual + bn)
__global__ __launch_bounds__(256) void k_bn_res(float* __restrict__ atom,
                                                const float* __restrict__ outb,
                                                const float* __restrict__ scl,
                                                const float* __restrict__ shf) {
    __shared__ float sc[16], sh[16];
    int tid = threadIdx.x;
    if (tid < 16) { sc[tid] = scl[tid]; sh[tid] = shf[tid]; }
    __syncthreads();
    const long total = (long)NN * CC * PP;
    for (long i = (long)blockIdx.x * blockDim.x + tid; i < total;
         i += (long)gridDim.x * blockDim.x) {
        int c = (int)((i / PP) & 15);
        atom[i] += sc[c] * outb[i] + sh[c];
    }
}

// ---------------- mean pooling over graphs (atomic) -------------------------
__global__ __launch_bounds__(256) void k_pool(const float* __restrict__ atom,
                                              const int* __restrict__ gi,
                                              float* __restrict__ crys) {
    int n = blockIdx.x;
    int g = gi[n];
    const float* a = &atom[(size_t)n * CC * PP];
    float* cr = &crys[(size_t)g * CC * PP];
    for (int i = threadIdx.x; i < CC * PP; i += 256) unsafeAtomicAdd(&cr[i], a[i]);
}

// ---------------- conv_to_fc: flat = softplus(conv16->16(crys/cnt)+b) -------
__global__ __launch_bounds__(256) void k_ctf(const float* __restrict__ crys,
                                             const int* __restrict__ counts,
                                             const float* __restrict__ w,
                                             const float* __restrict__ b,
                                             float* __restrict__ flat) {
    __shared__ float tile[CC * PP];
    __shared__ float ws[CC * CC * 9];
    __shared__ float bs[CC];
    int g = blockIdx.x, tid = threadIdx.x;
    float cnt = (float)counts[g];
    for (int i = tid; i < CC * PP; i += 256) tile[i] = crys[(size_t)g * CC * PP + i] / cnt;
    for (int i = tid; i < CC * CC * 9; i += 256) ws[i] = w[i];
    if (tid < CC) bs[tid] = b[tid];
    __syncthreads();
    for (int i = tid; i < CC * PP; i += 256) {
        int co = i / PP, p = i - co * PP, y = p / WW, x = p - (p / WW) * WW;
        float acc = bs[co];
#pragma unroll
        for (int dy = 0; dy < 3; dy++) {
            int yy = y + dy - 1; if ((unsigned)yy >= (unsigned)HH) continue;
#pragma unroll
            for (int dx = 0; dx < 3; dx++) {
                int xx = x + dx - 1; if ((unsigned)xx >= (unsigned)WW) continue;
                int zoff = yy * WW + xx, tap = dy * 3 + dx;
                const float* tp = &tile[zoff];
                const float* wp = &ws[co * 144 + tap];
#pragma unroll
                for (int ci = 0; ci < CC; ci++) acc += tp[ci * PP] * wp[ci * 9];
            }
        }
        flat[(size_t)g * CC * PP + i] = sp_f(acc);
    }
}

// ---------------- space branch --------------------------------------------
__global__ __launch_bounds__(256) void k_space1(const int* __restrict__ nsites,
                                                const int* __restrict__ sgs,
                                                const float* __restrict__ w1,
                                                const float* __restrict__ b1,
                                                const float* __restrict__ w2,
                                                const float* __restrict__ b2,
                                                const float* __restrict__ cw,
                                                const float* __restrict__ cb,
                                                float* __restrict__ sembp) {
    __shared__ float outer[256];
    __shared__ float row[16], col[16];
    __shared__ float cws[144], cbs[16];
    int g = blockIdx.x, tid = threadIdx.x;
    if (tid < 16) {
        float ns = (float)nsites[g], sg = (float)sgs[g];
        row[tid] = ns * w1[2 * tid] + sg * w1[2 * tid + 1] + b1[tid];
        col[tid] = ns * w2[2 * tid] + sg * w2[2 * tid + 1] + b2[tid];
        cbs[tid] = cb[tid];
    }
    if (tid >= 64 && tid < 64 + 144) cws[tid - 64] = cw[tid - 64];
    __syncthreads();
    outer[tid] = row[tid >> 4] * col[tid & 15];
    __syncthreads();
    for (int i = tid; i < 16 * 256; i += 256) {
        int c = i >> 8, p = i & 255, y = p >> 4, x = p & 15;
        float acc = cbs[c];
#pragma unroll
        for (int dy = 0; dy < 3; dy++) {
            int yy = y + dy - 1; if ((unsigned)yy >= 16u) continue;
#pragma unroll
            for (int dx = 0; dx < 3; dx++) {
                int xx = x + dx - 1; if ((unsigned)xx >= 16u) continue;
                acc += outer[yy * 16 + xx] * cws[c * 9 + dy * 3 + dx];
            }
        }
        sembp[(size_t)g * 4096 + i] = acc;
    }
}

// bn-apply + softplus, layout (B,16,16,16)
__global__ __launch_bounds__(256) void k_bn_sp256(const float* __restrict__ X,
                                                  float* __restrict__ Y,
                                                  const float* __restrict__ scl,
                                                  const float* __restrict__ shf) {
    __shared__ float sc[16], sh[16];
    if (threadIdx.x < 16) { sc[threadIdx.x] = scl[threadIdx.x]; sh[threadIdx.x] = shf[threadIdx.x]; }
    __syncthreads();
    int total = BB * 16 * 256;
    for (int i = blockIdx.x * blockDim.x + threadIdx.x; i < total;
         i += gridDim.x * blockDim.x) {
        int c = (i >> 8) & 15;
        Y[i] = sp_f(sc[c] * X[i] + sh[c]);
    }
}

__global__ __launch_bounds__(256) void k_space_conv(const float* __restrict__ X,
                                                    const float* __restrict__ w,
                                                    const float* __restrict__ b,
                                                    float* __restrict__ Y) {
    __shared__ float tile[16 * 256];  // 16KB
    __shared__ float ws[2304], bs[16];
    int g = blockIdx.x, tid = threadIdx.x;
    for (int i = tid; i < 4096; i += 256) tile[i] = X[(size_t)g * 4096 + i];
    for (int i = tid; i < 2304; i += 256) ws[i] = w[i];
    if (tid < 16) bs[tid] = b[tid];
    __syncthreads();
    for (int i = tid; i < 4096; i += 256) {
        int c = i >> 8, p = i & 255, y = p >> 4, x = p & 15;
        float acc = bs[c];
#pragma unroll
        for (int dy = 0; dy < 3; dy++) {
            int yy = y + dy - 1; if ((unsigned)yy >= 16u) continue;
#pragma unroll
            for (int dx = 0; dx < 3; dx++) {
                int xx = x + dx - 1; if ((unsigned)xx >= 16u) continue;
                int tap = dy * 3 + dx;
                const float* wp = &ws[c * 144 + tap];
                const float* tp = &tile[yy * 16 + xx];
#pragma unroll
                for (int ci = 0; ci < 16; ci++) acc += tp[ci * 256] * wp[ci * 9];
            }
        }
        Y[(size_t)g * 4096 + i] = acc;
    }
}

// bn -> maxpool 5x5/5 -> softplus -> dot fc3 ; sout[g] = sflat.fc3w + fc3b
__global__ __launch_bounds__(256) void k_space_tail(const float* __restrict__ ypre,
                                                    const float* __restrict__ scl,
                                                    const float* __restrict__ shf,
                                                    const float* __restrict__ fc3w,
                                                    const float* __restrict__ fc3b,
                                                    float* __restrict__ sout) {
    __shared__ float red[256];
    int g = blockIdx.x, tid = threadIdx.x;
    float val = 0.f;
    if (tid < 144) {
        int c = tid / 9, cell = tid - c * 9, py = cell / 3, px = cell - py * 3;
        float sc = scl[c], sh = shf[c];
        float mx = -INFINITY;
        const float* base = &ypre[((size_t)g * 16 + c) * 256];
        for (int yy = py * 5; yy < py * 5 + 5; yy++)
            for (int xx = px * 5; xx < px * 5 + 5; xx++)
                mx = fmaxf(mx, sc * base[yy * 16 + xx] + sh);
        val = sp_f(mx) * fc3w[tid];
    }
    red[tid] = val;
    __syncthreads();
    for (int off = 128; off > 0; off >>= 1) {
        if (tid < off) red[tid] += red[tid + off];
        __syncthreads();
    }
    if (tid == 0) sout[g] = red[0] + fc3b[0];
}

// ---------------- FC head --------------------------------------------------
__global__ __launch_bounds__(256) void k_head(const float* __restrict__ flat,
                                              const float* __restrict__ fc1w,
                                              const float* __restrict__ fc1b,
                                              const float* __restrict__ fc2w,
                                              const float* __restrict__ fc2b,
                                              const float* __restrict__ regw,
                                              const float* __restrict__ regb,
                                              const float* __restrict__ sout,
                                              const float* __restrict__ eps,
                                              float* __restrict__ out) {
    int g = blockIdx.x, tid = threadIdx.x;
    __shared__ float h1[32], h2[32];
    int o = tid >> 3, r = tid & 7;
    float part = 0.f;
    const float* fr = &flat[(size_t)g * 2016];
    const float* wr = &fc1w[(size_t)o * 2016];
    for (int j = r; j < 2016; j += 8) part += fr[j] * wr[j];
    part += __shfl_down(part, 4, 8);
    part += __shfl_down(part, 2, 8);
    part += __shfl_down(part, 1, 8);
    if (r == 0) h1[o] = sp_f(part + fc1b[o]);
    __syncthreads();
    if (tid < 32) {
        float a = fc2b[tid];
        for (int j = 0; j < 32; j++) a += h1[j] * fc2w[tid * 32 + j];
        h2[tid] = sp_f(a);
    }
    __syncthreads();
    if (tid == 0) {
        float a = regb[0];
        for (int j = 0; j < 32; j++) a += h2[j] * regw[j];
        out[g] = a + eps[0] * sout[g];
    }
}

// ===========================================================================
extern "C" void kernel_launch(void* const* d_in, const int* in_sizes, int n_in,
                              void* d_out, int out_size, void* d_ws, size_t ws_size,
                              hipStream_t stream) {
    const float* nodes   = (const float*)d_in[0];
    const int*   es      = (const int*)d_in[1];
    const int*   et      = (const int*)d_in[2];
    const int*   gi      = (const int*)d_in[3];
    const int*   cnt     = (const int*)d_in[4];
    const int*   nsites  = (const int*)d_in[5];
    const int*   sgs     = (const int*)d_in[6];
    const float* emb_w   = (const float*)d_in[7];
    const float* emb_b   = (const float*)d_in[8];
    const float* cl_nw   = (const float*)d_in[9];
    const float* cl_ew   = (const float*)d_in[10];
    const float* cl_lw   = (const float*)d_in[11];
    const float* cl_lb   = (const float*)d_in[12];
    const float* cl_bg   = (const float*)d_in[13];
    const float* cl_bb   = (const float*)d_in[14];
    const float* se_w1   = (const float*)d_in[15];
    const float* se_b1   = (const float*)d_in[16];
    const float* se_w2   = (const float*)d_in[17];
    const float* se_b2   = (const float*)d_in[18];
    const float* se_cw   = (const float*)d_in[19];
    const float* se_cb   = (const float*)d_in[20];
    const float* se_bg   = (const float*)d_in[21];
    const float* se_bb   = (const float*)d_in[22];
    const float* sf_cw   = (const float*)d_in[23];
    const float* sf_cb   = (const float*)d_in[24];
    const float* sf_bg   = (const float*)d_in[25];
    const float* sf_bb   = (const float*)d_in[26];
    const float* ctf_w   = (const float*)d_in[27];
    const float* ctf_b   = (const float*)d_in[28];
    const float* fc1_w   = (const float*)d_in[29];
    const float* fc1_b   = (const float*)d_in[30];
    const float* fc2_w   = (const float*)d_in[31];
    const float* fc2_b   = (const float*)d_in[32];
    const float* reg_w   = (const float*)d_in[33];
    const float* reg_b   = (const float*)d_in[34];
    const float* fc3_w   = (const float*)d_in[35];
    const float* fc3_b   = (const float*)d_in[36];
    const float* eps     = (const float*)d_in[37];
    float* out = (float*)d_out;

    const size_t ATOM_B = (size_t)NN * CC * PP * sizeof(float);  // 33,030,144
    char* ws = (char*)d_ws;
    float*  atom  = (float*)ws;              ws += ATOM_B;
    float*  An    = (float*)ws;              ws += ATOM_B;
    float*  Ae    = (float*)ws;              ws += ATOM_B;
    float*  outb  = (float*)ws;              ws += ATOM_B;
    double* acc   = (double*)ws;             ws += 256;
    float*  scl   = (float*)ws;              ws += 256;
    float*  shf   = (float*)ws;              ws += 256;
    float*  sout  = (float*)ws;              ws += 256;
    float*  nwT   = (float*)ws;              ws += 4608 * sizeof(float);
    float*  lwT   = (float*)ws;              ws += 4608 * sizeof(float);
    float*  crys  = (float*)ws;              ws += (size_t)BB * CC * PP * sizeof(float);
    float*  flat  = (float*)ws;              ws += (size_t)BB * CC * PP * sizeof(float);
    float*  sembp = (float*)ws;              ws += (size_t)BB * 16 * 256 * sizeof(float);
    float*  semb  = (float*)ws;              ws += (size_t)BB * 16 * 256 * sizeof(float);
    float*  ypre  = (float*)ws;              ws += (size_t)BB * 16 * 256 * sizeof(float);

    // ---- embedding
    k_embed<<<NN, 256, 0, stream>>>(nodes, emb_w, emb_b, atom);

    // ---- 3 conv layers
    for (int l = 0; l < 3; l++) {
        const float* nw = cl_nw + (size_t)l * CC * CC * 9;
        const float* ew = cl_ew + (size_t)l * CC * CC * 9;
        const float* lw = cl_lw + (size_t)l * 32 * CC * 9;
        const float* lb = cl_lb + (size_t)l * 32;
        const float* bg = cl_bg + (size_t)l * 16;
        const float* bb = cl_bb + (size_t)l * 16;

        k_wT2<<<9, 256, 0, stream>>>(nw, ew, nwT);
        k_wT<<<18, 256, 0, stream>>>(lw, lwT);
        k_node_conv2<<<NN, 128, 0, stream>>>(atom, nwT, An, Ae);
        hipMemcpyAsync(outb, atom, ATOM_B, hipMemcpyDeviceToDevice, stream);
        k_edge<<<EE, 128, 0, stream>>>(An, Ae, es, et, lwT, lb, outb);
        hipMemsetAsync(acc, 0, 16 * 2 * sizeof(double), stream);
        k_bn_stats<16, 126><<<dim3(64, 16), 128, 0, stream>>>(outb, acc, NN);
        k_bn_fin<<<1, 16, 0, stream>>>(acc, bg, bb, 1.0 / ((double)NN * PP), scl, shf);
        k_bn_res<<<2048, 256, 0, stream>>>(atom, outb, scl, shf);
    }

    // ---- space branch
    k_space1<<<BB, 256, 0, stream>>>(nsites, sgs, se_w1, se_b1, se_w2, se_b2,
                                     se_cw, se_cb, sembp);
    hipMemsetAsync(acc, 0, 16 * 2 * sizeof(double), stream);
    k_bn_stats<16, 256><<<dim3(8, 16), 256, 0, stream>>>(sembp, acc, BB);
    k_bn_fin<<<1, 16, 0, stream>>>(acc, se_bg, se_bb, 1.0 / (BB * 256.0), scl, shf);
    k_bn_sp256<<<256, 256, 0, stream>>>(sembp, semb, scl, shf);
    k_space_conv<<<BB, 256, 0, stream>>>(semb, sf_cw, sf_cb, ypre);
    hipMemsetAsync(acc, 0, 16 * 2 * sizeof(double), stream);
    k_bn_stats<16, 256><<<dim3(8, 16), 256, 0, stream>>>(ypre, acc, BB);
    k_bn_fin<<<1, 16, 0, stream>>>(acc, sf_bg, sf_bb, 1.0 / (BB * 256.0), scl, shf);
    k_space_tail<<<BB, 256, 0, stream>>>(ypre, scl, shf, fc3_w, fc3_b, sout);

    // ---- pooling + conv_to_fc + head
    hipMemsetAsync(crys, 0, (size_t)BB * CC * PP * sizeof(float), stream);
    k_pool<<<NN, 256, 0, stream>>>(atom, gi, crys);
    k_ctf<<<BB, 256, 0, stream>>>(crys, cnt, ctf_w, ctf_b, flat);
    k_head<<<BB, 256, 0, stream>>>(flat, fc1_w, fc1_b, fc2_w, fc2_b,
                                   reg_w, reg_b, sout, eps, out);
}

// Round 3
// 1939.133 us; speedup vs baseline: 3.0700x; 3.0700x over previous
//
#include <hip/hip_runtime.h>
#include <math.h>

#define HH 7
#define WW 18
#define PP 126        // HH*WW
#define CC 16
#define NN 4096
#define EE 16384
#define BB 64
#define RPAD 20                 // padded row length
#define NPAD (CC * HH * RPAD)   // 2240 floats per node tile (padded)

__device__ __forceinline__ float sp_f(float x) {
    // softplus, JAX-stable form: max(x,0)+log1p(exp(-|x|))
    return fmaxf(x, 0.f) + log1pf(expf(-fabsf(x)));
}

// ---------------- weight transposes -> [tap][ci][co][2] ---------------------
// lin weights (32 out-ch): half0 = filter (co<16), half1 = core (co>=16)
__global__ void k_wT(const float* __restrict__ w, float* __restrict__ wT) {
    int i = blockIdx.x * 256 + threadIdx.x;
    if (i < 32 * 144) {
        int co = i / 144, r = i - co * 144, ci = r / 9, tap = r - ci * 9;
        int half = co >> 4, coo = co & 15;
        wT[((tap * 16 + ci) * 16 + coo) * 2 + half] = w[i];
    }
}
// node+edge weights packed: half0 = node, half1 = edge
__global__ void k_wT2(const float* __restrict__ wN, const float* __restrict__ wE,
                      float* __restrict__ wT) {
    int i = blockIdx.x * 256 + threadIdx.x;
    if (i < 16 * 144) {
        int co = i / 144, r = i - co * 144, ci = r / 9, tap = r - ci * 9;
        wT[((tap * 16 + ci) * 16 + co) * 2 + 0] = wN[i];
        wT[((tap * 16 + ci) * 16 + co) * 2 + 1] = wE[i];
    }
}

// ---------------- embedding: atom = softplus(conv1->16(nodes) + b) ----------
__global__ __launch_bounds__(256) void k_embed(const float* __restrict__ nodes,
                                               const float* __restrict__ w,
                                               const float* __restrict__ b,
                                               float* __restrict__ atom) {
    __shared__ float tile[PP];
    __shared__ float ws[CC * 9];
    __shared__ float bs[CC];
    int n = blockIdx.x, tid = threadIdx.x;
    for (int i = tid; i < PP; i += 256) tile[i] = nodes[n * PP + i];
    for (int i = tid; i < CC * 9; i += 256) ws[i] = w[i];
    if (tid < CC) bs[tid] = b[tid];
    __syncthreads();
    for (int i = tid; i < CC * PP; i += 256) {
        int c = i / PP, p = i - c * PP, y = p / WW, x = p - (p / WW) * WW;
        float acc = bs[c];
#pragma unroll
        for (int dy = 0; dy < 3; dy++) {
            int yy = y + dy - 1; if ((unsigned)yy >= (unsigned)HH) continue;
#pragma unroll
            for (int dx = 0; dx < 3; dx++) {
                int xx = x + dx - 1; if ((unsigned)xx >= (unsigned)WW) continue;
                acc += tile[yy * WW + xx] * ws[c * 9 + dy * 3 + dx];
            }
        }
        atom[(size_t)n * CC * PP + i] = sp_f(acc);
    }
}

// core conv macro body: accumulate (hA,hB) over ci,dy from padded LDS tile
// zt: base of [16][7][20] tile; ws4: [9][16][16][2]
#define CONV_BODY(ZT, HA, HB)                                                   \
    for (int ci = 0; ci < 16; ci++) {                                           \
        const float* zb = (ZT) + ci * (HH * RPAD);                              \
        _Pragma("unroll")                                                       \
        for (int dy = 0; dy < 3; dy++) {                                        \
            int yy = y + dy - 1;                                                \
            if ((unsigned)yy < (unsigned)HH) {                                  \
                const float* zr = zb + yy * RPAD;                               \
                float4 q0 = *(const float4*)&zr[0];                             \
                float4 q1 = *(const float4*)&zr[4];                             \
                float4 q2 = *(const float4*)&zr[8];                             \
                float4 q3 = *(const float4*)&zr[12];                            \
                float2 q4 = *(const float2*)&zr[16];                            \
                float r[18] = {q0.x, q0.y, q0.z, q0.w, q1.x, q1.y, q1.z, q1.w,  \
                               q2.x, q2.y, q2.z, q2.w, q3.x, q3.y, q3.z, q3.w,  \
                               q4.x, q4.y};                                     \
                float2 w0 = *(const float2*)&ws[dy * 3 + 0][ci][co][0];         \
                float2 w1 = *(const float2*)&ws[dy * 3 + 1][ci][co][0];         \
                float2 w2 = *(const float2*)&ws[dy * 3 + 2][ci][co][0];         \
                _Pragma("unroll")                                               \
                for (int x = 0; x < 18; x++) {                                  \
                    float a0 = r[x] * w1.x, a1 = r[x] * w1.y;                   \
                    if (x > 0)  { a0 += r[x - 1] * w0.x; a1 += r[x - 1] * w0.y; }\
                    if (x < 17) { a0 += r[x + 1] * w2.x; a1 += r[x + 1] * w2.y; }\
                    HA[x] += a0; HB[x] += a1;                                   \
                }                                                               \
            }                                                                   \
        }                                                                       \
    }

// ------------- per-node dual conv 16->16, 2 nodes/block ---------------------
// atom: std layout [N][16][126]; An/Ae out: padded layout [N][16][7][20]
__global__ __launch_bounds__(256) void k_node_conv2(const float* __restrict__ atom,
                                                    const float* __restrict__ wT,
                                                    float* __restrict__ An,
                                                    float* __restrict__ Ae) {
    __shared__ __align__(16) float z[2 * NPAD];        // 4480 fl
    __shared__ __align__(16) float ws[9][16][16][2];   // 4608 fl
    int tid = threadIdx.x;
    int n0 = blockIdx.x * 2;
    // load std -> padded LDS (pads zeroed)
    for (int i = tid; i < 2 * NPAD; i += 256) {
        int e2 = i / NPAD, r = i - e2 * NPAD;
        int ci = r / (HH * RPAD), rr = r - ci * (HH * RPAD);
        int y = rr / RPAD, x = rr - y * RPAD;
        float v = 0.f;
        if (x < WW) v = atom[(size_t)(n0 + e2) * CC * PP + ci * PP + y * WW + x];
        z[i] = v;
    }
    for (int i = tid; i < 4608; i += 256) ((float*)ws)[i] = wT[i];
    __syncthreads();
    int grp = tid >> 7, lt = tid & 127;
    float hN[18], hE[18];
    bool act = lt < 112;
    int co = lt & 15, y = lt >> 4;
    if (act) {
#pragma unroll
        for (int x = 0; x < 18; x++) { hN[x] = 0.f; hE[x] = 0.f; }
        const float* zt = &z[grp * NPAD];
        CONV_BODY(zt, hN, hE)
    }
    __syncthreads();
    // stage into padded layout: hN -> z area, hE -> ws area
    float* sN = z;
    float* sE = (float*)ws;
    if (act) {
        int base = grp * NPAD + co * (HH * RPAD) + y * RPAD;
#pragma unroll
        for (int x = 0; x < 18; x++) { sN[base + x] = hN[x]; sE[base + x] = hE[x]; }
        sN[base + 18] = 0.f; sN[base + 19] = 0.f;
        sE[base + 18] = 0.f; sE[base + 19] = 0.f;
    }
    __syncthreads();
    // coalesced float4 copy-out
    const float4* sN4 = (const float4*)sN;
    const float4* sE4 = (const float4*)sE;
    for (int i = tid; i < 2 * (NPAD / 4); i += 256) {
        int e2 = i / (NPAD / 4), j = i - e2 * (NPAD / 4);
        ((float4*)&An[(size_t)(n0 + e2) * NPAD])[j] = sN4[i];
        ((float4*)&Ae[(size_t)(n0 + e2) * NPAD])[j] = sE4[i];
    }
}

// ---------------- per-edge, 2 edges/block -----------------------------------
// z=elu(An[s]*Ae[t]) (padded layout in, pads 0); h=conv16->32(z)+lb;
// msg=sigmoid(h[:16])*softplus(h[16:]); outb[s] += msg (std layout, coalesced)
__global__ __launch_bounds__(256) void k_edge(const float* __restrict__ An,
                                              const float* __restrict__ Ae,
                                              const int* __restrict__ es,
                                              const int* __restrict__ et,
                                              const float* __restrict__ lwT,
                                              const float* __restrict__ lb,
                                              float* __restrict__ outb) {
    __shared__ __align__(16) float z[2 * NPAD];        // 4480 fl
    __shared__ __align__(16) float ws[9][16][16][2];   // 4608 fl
    int tid = threadIdx.x;
    int e0 = blockIdx.x * 2;
    int s0 = es[e0], t0 = et[e0], s1 = es[e0 + 1], t1 = et[e0 + 1];
    // load: z = elu(an*ae), float4 all the way (pads: 0*0 -> elu(0)=0)
    for (int i = tid; i < 2 * (NPAD / 4); i += 256) {
        int e2 = i / (NPAD / 4), j = i - e2 * (NPAD / 4);
        int s = e2 ? s1 : s0, t = e2 ? t1 : t0;
        float4 av = ((const float4*)&An[(size_t)s * NPAD])[j];
        float4 ev = ((const float4*)&Ae[(size_t)t * NPAD])[j];
        float4 res;
        res.x = av.x * ev.x; res.x = res.x > 0.f ? res.x : expm1f(res.x);
        res.y = av.y * ev.y; res.y = res.y > 0.f ? res.y : expm1f(res.y);
        res.z = av.z * ev.z; res.z = res.z > 0.f ? res.z : expm1f(res.z);
        res.w = av.w * ev.w; res.w = res.w > 0.f ? res.w : expm1f(res.w);
        ((float4*)z)[i] = res;
    }
    for (int i = tid; i < 4608; i += 256) ((float*)ws)[i] = lwT[i];
    __syncthreads();
    int grp = tid >> 7, lt = tid & 127;
    bool act = lt < 112;
    int co = lt & 15, y = lt >> 4;
    float msg[18];
    if (act) {
        float hf[18], hc[18];
#pragma unroll
        for (int x = 0; x < 18; x++) { hf[x] = 0.f; hc[x] = 0.f; }
        const float* zt = &z[grp * NPAD];
        CONV_BODY(zt, hf, hc)
        float bf = lb[co], bc = lb[co + 16];
#pragma unroll
        for (int x = 0; x < 18; x++) {
            float hfv = hf[x] + bf, hcv = hc[x] + bc;
            float sig = 1.f / (1.f + expf(-hfv));
            msg[x] = sig * sp_f(hcv);
        }
    }
    __syncthreads();
    // stage msg into std layout [2][16][126] (z area is dead)
    float* msgL = z;
    if (act) {
        int base = grp * (CC * PP) + co * PP + y * WW;
#pragma unroll
        for (int x = 0; x < 18; x++) msgL[base + x] = msg[x];
    }
    __syncthreads();
    // coalesced atomic scatter
    for (int i = tid; i < 2 * CC * PP; i += 256) {
        int e2 = i / (CC * PP), j = i - e2 * (CC * PP);
        int s = e2 ? s1 : s0;
        unsafeAtomicAdd(&outb[(size_t)s * CC * PP + j], msgL[i]);
    }
}

// ---------------- BN statistics (double accumulation) -----------------------
template <int C, int S>
__global__ void k_bn_stats(const float* __restrict__ X, double* __restrict__ acc, int M) {
    int c = blockIdx.y, tid = threadIdx.x;
    double s1 = 0.0, s2 = 0.0;
    for (int m = blockIdx.x; m < M; m += gridDim.x) {
        const float* xr = &X[((size_t)m * C + c) * S];
        for (int s = tid; s < S; s += blockDim.x) {
            float v = xr[s];
            s1 += v; s2 += (double)v * v;
        }
    }
    __shared__ double sh1[256], sh2[256];
    sh1[tid] = s1; sh2[tid] = s2;
    __syncthreads();
    for (int off = blockDim.x >> 1; off > 0; off >>= 1) {
        if (tid < off) { sh1[tid] += sh1[tid + off]; sh2[tid] += sh2[tid + off]; }
        __syncthreads();
    }
    if (tid == 0) {
        unsafeAtomicAdd(&acc[2 * c], sh1[0]);
        unsafeAtomicAdd(&acc[2 * c + 1], sh2[0]);
    }
}

__global__ void k_bn_fin(const double* __restrict__ acc, const float* __restrict__ g,
                         const float* __restrict__ b, double invn,
                         float* __restrict__ scl, float* __restrict__ shf) {
    int c = threadIdx.x;
    if (c < 16) {
        double m = acc[2 * c] * invn;
        double v = acc[2 * c + 1] * invn - m * m;
        double s = (double)g[c] / sqrt(v + 1e-5);
        scl[c] = (float)s;
        shf[c] = (float)((double)b[c] - s * m);
    }
}

// atom += scl[c]*outb + shf[c]     (residual + bn)
__global__ __launch_bounds__(256) void k_bn_res(float* __restrict__ atom,
                                                const float* __restrict__ outb,
                                                const float* __restrict__ scl,
                                                const float* __restrict__ shf) {
    __shared__ float sc[16], sh[16];
    int tid = threadIdx.x;
    if (tid < 16) { sc[tid] = scl[tid]; sh[tid] = shf[tid]; }
    __syncthreads();
    const long total = (long)NN * CC * PP;
    for (long i = (long)blockIdx.x * blockDim.x + tid; i < total;
         i += (long)gridDim.x * blockDim.x) {
        int c = (int)((i / PP) & 15);
        atom[i] += sc[c] * outb[i] + sh[c];
    }
}

// ---------------- mean pooling over graphs (atomic) -------------------------
__global__ __launch_bounds__(256) void k_pool(const float* __restrict__ atom,
                                              const int* __restrict__ gi,
                                              float* __restrict__ crys) {
    int n = blockIdx.x;
    int g = gi[n];
    const float* a = &atom[(size_t)n * CC * PP];
    float* cr = &crys[(size_t)g * CC * PP];
    for (int i = threadIdx.x; i < CC * PP; i += 256) unsafeAtomicAdd(&cr[i], a[i]);
}

// ---------------- conv_to_fc: flat = softplus(conv16->16(crys/cnt)+b) -------
__global__ __launch_bounds__(256) void k_ctf(const float* __restrict__ crys,
                                             const int* __restrict__ counts,
                                             const float* __restrict__ w,
                                             const float* __restrict__ b,
                                             float* __restrict__ flat) {
    __shared__ float tile[CC * PP];
    __shared__ float ws[CC * CC * 9];
    __shared__ float bs[CC];
    int g = blockIdx.x, tid = threadIdx.x;
    float cnt = (float)counts[g];
    for (int i = tid; i < CC * PP; i += 256) tile[i] = crys[(size_t)g * CC * PP + i] / cnt;
    for (int i = tid; i < CC * CC * 9; i += 256) ws[i] = w[i];
    if (tid < CC) bs[tid] = b[tid];
    __syncthreads();
    for (int i = tid; i < CC * PP; i += 256) {
        int co = i / PP, p = i - co * PP, y = p / WW, x = p - (p / WW) * WW;
        float acc = bs[co];
#pragma unroll
        for (int dy = 0; dy < 3; dy++) {
            int yy = y + dy - 1; if ((unsigned)yy >= (unsigned)HH) continue;
#pragma unroll
            for (int dx = 0; dx < 3; dx++) {
                int xx = x + dx - 1; if ((unsigned)xx >= (unsigned)WW) continue;
                int zoff = yy * WW + xx, tap = dy * 3 + dx;
                const float* tp = &tile[zoff];
                const float* wp = &ws[co * 144 + tap];
#pragma unroll
                for (int ci = 0; ci < CC; ci++) acc += tp[ci * PP] * wp[ci * 9];
            }
        }
        flat[(size_t)g * CC * PP + i] = sp_f(acc);
    }
}

// ---------------- space branch --------------------------------------------
__global__ __launch_bounds__(256) void k_space1(const int* __restrict__ nsites,
                                                const int* __restrict__ sgs,
                                                const float* __restrict__ w1,
                                                const float* __restrict__ b1,
                                                const float* __restrict__ w2,
                                                const float* __restrict__ b2,
                                                const float* __restrict__ cw,
                                                const float* __restrict__ cb,
                                                float* __restrict__ sembp) {
    __shared__ float outer[256];
    __shared__ float row[16], col[16];
    __shared__ float cws[144], cbs[16];
    int g = blockIdx.x, tid = threadIdx.x;
    if (tid < 16) {
        float ns = (float)nsites[g], sg = (float)sgs[g];
        row[tid] = ns * w1[2 * tid] + sg * w1[2 * tid + 1] + b1[tid];
        col[tid] = ns * w2[2 * tid] + sg * w2[2 * tid + 1] + b2[tid];
        cbs[tid] = cb[tid];
    }
    if (tid >= 64 && tid < 64 + 144) cws[tid - 64] = cw[tid - 64];
    __syncthreads();
    outer[tid] = row[tid >> 4] * col[tid & 15];
    __syncthreads();
    for (int i = tid; i < 16 * 256; i += 256) {
        int c = i >> 8, p = i & 255, y = p >> 4, x = p & 15;
        float acc = cbs[c];
#pragma unroll
        for (int dy = 0; dy < 3; dy++) {
            int yy = y + dy - 1; if ((unsigned)yy >= 16u) continue;
#pragma unroll
            for (int dx = 0; dx < 3; dx++) {
                int xx = x + dx - 1; if ((unsigned)xx >= 16u) continue;
                acc += outer[yy * 16 + xx] * cws[c * 9 + dy * 3 + dx];
            }
        }
        sembp[(size_t)g * 4096 + i] = acc;
    }
}

// bn-apply + softplus, layout (B,16,16,16)
__global__ __launch_bounds__(256) void k_bn_sp256(const float* __restrict__ X,
                                                  float* __restrict__ Y,
                                                  const float* __restrict__ scl,
                                                  const float* __restrict__ shf) {
    __shared__ float sc[16], sh[16];
    if (threadIdx.x < 16) { sc[threadIdx.x] = scl[threadIdx.x]; sh[threadIdx.x] = shf[threadIdx.x]; }
    __syncthreads();
    int total = BB * 16 * 256;
    for (int i = blockIdx.x * blockDim.x + threadIdx.x; i < total;
         i += gridDim.x * blockDim.x) {
        int c = (i >> 8) & 15;
        Y[i] = sp_f(sc[c] * X[i] + sh[c]);
    }
}

__global__ __launch_bounds__(256) void k_space_conv(const float* __restrict__ X,
                                                    const float* __restrict__ w,
                                                    const float* __restrict__ b,
                                                    float* __restrict__ Y) {
    __shared__ float tile[16 * 256];  // 16KB
    __shared__ float ws[2304], bs[16];
    int g = blockIdx.x, tid = threadIdx.x;
    for (int i = tid; i < 4096; i += 256) tile[i] = X[(size_t)g * 4096 + i];
    for (int i = tid; i < 2304; i += 256) ws[i] = w[i];
    if (tid < 16) bs[tid] = b[tid];
    __syncthreads();
    for (int i = tid; i < 4096; i += 256) {
        int c = i >> 8, p = i & 255, y = p >> 4, x = p & 15;
        float acc = bs[c];
#pragma unroll
        for (int dy = 0; dy < 3; dy++) {
            int yy = y + dy - 1; if ((unsigned)yy >= 16u) continue;
#pragma unroll
            for (int dx = 0; dx < 3; dx++) {
                int xx = x + dx - 1; if ((unsigned)xx >= 16u) continue;
                int tap = dy * 3 + dx;
                const float* wp = &ws[c * 144 + tap];
                const float* tp = &tile[yy * 16 + xx];
#pragma unroll
                for (int ci = 0; ci < 16; ci++) acc += tp[ci * 256] * wp[ci * 9];
            }
        }
        Y[(size_t)g * 4096 + i] = acc;
    }
}

// bn -> maxpool 5x5/5 -> softplus -> dot fc3 ; sout[g] = sflat.fc3w + fc3b
__global__ __launch_bounds__(256) void k_space_tail(const float* __restrict__ ypre,
                                                    const float* __restrict__ scl,
                                                    const float* __restrict__ shf,
                                                    const float* __restrict__ fc3w,
                                                    const float* __restrict__ fc3b,
                                                    float* __restrict__ sout) {
    __shared__ float red[256];
    int g = blockIdx.x, tid = threadIdx.x;
    float val = 0.f;
    if (tid < 144) {
        int c = tid / 9, cell = tid - c * 9, py = cell / 3, px = cell - py * 3;
        float sc = scl[c], sh = shf[c];
        float mx = -INFINITY;
        const float* base = &ypre[((size_t)g * 16 + c) * 256];
        for (int yy = py * 5; yy < py * 5 + 5; yy++)
            for (int xx = px * 5; xx < px * 5 + 5; xx++)
                mx = fmaxf(mx, sc * base[yy * 16 + xx] + sh);
        val = sp_f(mx) * fc3w[tid];
    }
    red[tid] = val;
    __syncthreads();
    for (int off = 128; off > 0; off >>= 1) {
        if (tid < off) red[tid] += red[tid + off];
        __syncthreads();
    }
    if (tid == 0) sout[g] = red[0] + fc3b[0];
}

// ---------------- FC head --------------------------------------------------
__global__ __launch_bounds__(256) void k_head(const float* __restrict__ flat,
                                              const float* __restrict__ fc1w,
                                              const float* __restrict__ fc1b,
                                              const float* __restrict__ fc2w,
                                              const float* __restrict__ fc2b,
                                              const float* __restrict__ regw,
                                              const float* __restrict__ regb,
                                              const float* __restrict__ sout,
                                              const float* __restrict__ eps,
                                              float* __restrict__ out) {
    int g = blockIdx.x, tid = threadIdx.x;
    __shared__ float h1[32], h2[32];
    int o = tid >> 3, r = tid & 7;
    float part = 0.f;
    const float* fr = &flat[(size_t)g * 2016];
    const float* wr = &fc1w[(size_t)o * 2016];
    for (int j = r; j < 2016; j += 8) part += fr[j] * wr[j];
    part += __shfl_down(part, 4, 8);
    part += __shfl_down(part, 2, 8);
    part += __shfl_down(part, 1, 8);
    if (r == 0) h1[o] = sp_f(part + fc1b[o]);
    __syncthreads();
    if (tid < 32) {
        float a = fc2b[tid];
        for (int j = 0; j < 32; j++) a += h1[j] * fc2w[tid * 32 + j];
        h2[tid] = sp_f(a);
    }
    __syncthreads();
    if (tid == 0) {
        float a = regb[0];
        for (int j = 0; j < 32; j++) a += h2[j] * regw[j];
        out[g] = a + eps[0] * sout[g];
    }
}

// ===========================================================================
extern "C" void kernel_launch(void* const* d_in, const int* in_sizes, int n_in,
                              void* d_out, int out_size, void* d_ws, size_t ws_size,
                              hipStream_t stream) {
    const float* nodes   = (const float*)d_in[0];
    const int*   es      = (const int*)d_in[1];
    const int*   et      = (const int*)d_in[2];
    const int*   gi      = (const int*)d_in[3];
    const int*   cnt     = (const int*)d_in[4];
    const int*   nsites  = (const int*)d_in[5];
    const int*   sgs     = (const int*)d_in[6];
    const float* emb_w   = (const float*)d_in[7];
    const float* emb_b   = (const float*)d_in[8];
    const float* cl_nw   = (const float*)d_in[9];
    const float* cl_ew   = (const float*)d_in[10];
    const float* cl_lw   = (const float*)d_in[11];
    const float* cl_lb   = (const float*)d_in[12];
    const float* cl_bg   = (const float*)d_in[13];
    const float* cl_bb   = (const float*)d_in[14];
    const float* se_w1   = (const float*)d_in[15];
    const float* se_b1   = (const float*)d_in[16];
    const float* se_w2   = (const float*)d_in[17];
    const float* se_b2   = (const float*)d_in[18];
    const float* se_cw   = (const float*)d_in[19];
    const float* se_cb   = (const float*)d_in[20];
    const float* se_bg   = (const float*)d_in[21];
    const float* se_bb   = (const float*)d_in[22];
    const float* sf_cw   = (const float*)d_in[23];
    const float* sf_cb   = (const float*)d_in[24];
    const float* sf_bg   = (const float*)d_in[25];
    const float* sf_bb   = (const float*)d_in[26];
    const float* ctf_w   = (const float*)d_in[27];
    const float* ctf_b   = (const float*)d_in[28];
    const float* fc1_w   = (const float*)d_in[29];
    const float* fc1_b   = (const float*)d_in[30];
    const float* fc2_w   = (const float*)d_in[31];
    const float* fc2_b   = (const float*)d_in[32];
    const float* reg_w   = (const float*)d_in[33];
    const float* reg_b   = (const float*)d_in[34];
    const float* fc3_w   = (const float*)d_in[35];
    const float* fc3_b   = (const float*)d_in[36];
    const float* eps     = (const float*)d_in[37];
    float* out = (float*)d_out;

    const size_t ATOM_B = (size_t)NN * CC * PP * sizeof(float);   // 33 MB
    const size_t PAD_B  = (size_t)NN * NPAD * sizeof(float);      // 36.7 MB
    char* ws = (char*)d_ws;
    float*  atom  = (float*)ws;              ws += ATOM_B;
    float*  An    = (float*)ws;              ws += PAD_B;
    float*  Ae    = (float*)ws;              ws += PAD_B;
    float*  outb  = (float*)ws;              ws += ATOM_B;
    double* acc   = (double*)ws;             ws += 256;
    float*  scl   = (float*)ws;              ws += 256;
    float*  shf   = (float*)ws;              ws += 256;
    float*  sout  = (float*)ws;              ws += 256;
    float*  nwT   = (float*)ws;              ws += 4608 * sizeof(float);
    float*  lwT   = (float*)ws;              ws += 4608 * sizeof(float);
    float*  crys  = (float*)ws;              ws += (size_t)BB * CC * PP * sizeof(float);
    float*  flat  = (float*)ws;              ws += (size_t)BB * CC * PP * sizeof(float);
    float*  sembp = (float*)ws;              ws += (size_t)BB * 16 * 256 * sizeof(float);
    float*  semb  = (float*)ws;              ws += (size_t)BB * 16 * 256 * sizeof(float);
    float*  ypre  = (float*)ws;              ws += (size_t)BB * 16 * 256 * sizeof(float);

    // ---- embedding
    k_embed<<<NN, 256, 0, stream>>>(nodes, emb_w, emb_b, atom);

    // ---- 3 conv layers
    for (int l = 0; l < 3; l++) {
        const float* nw = cl_nw + (size_t)l * CC * CC * 9;
        const float* ew = cl_ew + (size_t)l * CC * CC * 9;
        const float* lw = cl_lw + (size_t)l * 32 * CC * 9;
        const float* lb = cl_lb + (size_t)l * 32;
        const float* bg = cl_bg + (size_t)l * 16;
        const float* bb = cl_bb + (size_t)l * 16;

        k_wT2<<<9, 256, 0, stream>>>(nw, ew, nwT);
        k_wT<<<18, 256, 0, stream>>>(lw, lwT);
        k_node_conv2<<<NN / 2, 256, 0, stream>>>(atom, nwT, An, Ae);
        hipMemcpyAsync(outb, atom, ATOM_B, hipMemcpyDeviceToDevice, stream);
        k_edge<<<EE / 2, 256, 0, stream>>>(An, Ae, es, et, lwT, lb, outb);
        hipMemsetAsync(acc, 0, 16 * 2 * sizeof(double), stream);
        k_bn_stats<16, 126><<<dim3(64, 16), 128, 0, stream>>>(outb, acc, NN);
        k_bn_fin<<<1, 16, 0, stream>>>(acc, bg, bb, 1.0 / ((double)NN * PP), scl, shf);
        k_bn_res<<<2048, 256, 0, stream>>>(atom, outb, scl, shf);
    }

    // ---- space branch
    k_space1<<<BB, 256, 0, stream>>>(nsites, sgs, se_w1, se_b1, se_w2, se_b2,
                                     se_cw, se_cb, sembp);
    hipMemsetAsync(acc, 0, 16 * 2 * sizeof(double), stream);
    k_bn_stats<16, 256><<<dim3(8, 16), 256, 0, stream>>>(sembp, acc, BB);
    k_bn_fin<<<1, 16, 0, stream>>>(acc, se_bg, se_bb, 1.0 / (BB * 256.0), scl, shf);
    k_bn_sp256<<<256, 256, 0, stream>>>(sembp, semb, scl, shf);
    k_space_conv<<<BB, 256, 0, stream>>>(semb, sf_cw, sf_cb, ypre);
    hipMemsetAsync(acc, 0, 16 * 2 * sizeof(double), stream);
    k_bn_stats<16, 256><<<dim3(8, 16), 256, 0, stream>>>(ypre, acc, BB);
    k_bn_fin<<<1, 16, 0, stream>>>(acc, sf_bg, sf_bb, 1.0 / (BB * 256.0), scl, shf);
    k_space_tail<<<BB, 256, 0, stream>>>(ypre, scl, shf, fc3_w, fc3_b, sout);

    // ---- pooling + conv_to_fc + head
    hipMemsetAsync(crys, 0, (size_t)BB * CC * PP * sizeof(float), stream);
    k_pool<<<NN, 256, 0, stream>>>(atom, gi, crys);
    k_ctf<<<BB, 256, 0, stream>>>(crys, cnt, ctf_w, ctf_b, flat);
    k_head<<<BB, 256, 0, stream>>>(flat, fc1_w, fc1_b, fc2_w, fc2_b,
                                   reg_w, reg_b, sout, eps, out);
}